// Round 4
// baseline (255.914 us; speedup 1.0000x reference)
//
#include <hip/hip_runtime.h>
#include <math.h>

typedef unsigned short ushort_t;
typedef unsigned int   uint_t;
typedef __attribute__((ext_vector_type(8)))  short bf16x8;
typedef __attribute__((ext_vector_type(16))) float f32x16;
typedef __attribute__((ext_vector_type(2)))  float f32x2;

#define NPTS   65536   // B*P
#define NV     5023
#define LATD   32
#define KF     110
#define FSTR   112     // feat row stride (uints)
#define NPAIR  2512    // ceil(NV/2) vertex pairs per batch (vert 5023 = pad)
#define QPAIR  628     // pairs per wave-quarter (4*628 = 2512)

__device__ __forceinline__ ushort_t f2bf(float f) {
  union { float f; unsigned u; } x; x.f = f;
  unsigned r = x.u + 0x7fffu + ((x.u >> 16) & 1u);   // RNE
  return (ushort_t)(r >> 16);
}
__device__ __forceinline__ float bf2f(ushort_t u) {
  union { unsigned u; float f; } x; x.u = ((unsigned)u) << 16;
  return x.f;
}
__device__ __forceinline__ uint_t packsplit(float v) {
  const ushort_t h = f2bf(v);
  const ushort_t l = f2bf(v - bf2f(h));
  return (uint_t)h | ((uint_t)l << 16);
}

// ---------------- Kernel 0: prep (weight split+relayout, vertex prescale) ----------------
// weight panels (ushorts/plane), 9 x 16384, COALESCED layout:
//   offset(ks,tn,l31,lh,j) = (ks*4+tn)*512 + l31*16 + lh*8 + j  = W[tn*32+l31][ks*16+lh*8+j]
// vpre[b][pair][8] = {-2x0,-2x1,-2y0,-2y1,-2z0,-2z1,w0,w1}, w = fmaf(x,x,fmaf(y,y,z*z))
// (w is the EXACT t.w of the r7-verified metric; -2v is exact; pad vert: 0,0,0,3e38)
__global__ __launch_bounds__(256) void k_prep(
    const float* __restrict__ dm,
    const float* __restrict__ w0, const float* __restrict__ w1,
    const float* __restrict__ w2, const float* __restrict__ w3,
    const float* __restrict__ w4, const float* __restrict__ w5,
    const float* __restrict__ w6, const float* __restrict__ w7,
    ushort_t* __restrict__ wsWh, ushort_t* __restrict__ wsWl,
    float* __restrict__ vpre)
{
  const int e = blockIdx.x * 256 + threadIdx.x;    // 576*256 = 147456 exactly
  {
    const int p = e >> 14, local = e & 16383;
    const int j   = local & 7;
    const int lh  = (local >> 3) & 1;
    const int l31 = (local >> 4) & 31;
    const int tn  = (local >> 9) & 3;
    const int ks  = (local >> 11) & 7;
    const int n = tn*32 + l31;
    const int k = ks*16 + lh*8 + j;
    float v;
    if (p == 0)      v = (k < KF) ? w0[n*110 + k] : 0.f;
    else if (p == 1) v = w1[n*128 + k];
    else if (p == 2) v = w2[n*128 + k];
    else if (p == 3) v = w3[n*128 + k];
    else if (p == 4) v = (k < KF) ? w4[n*238 + k] : 0.f;
    else if (p == 5) v = w4[n*238 + KF + k];
    else if (p == 6) v = w5[n*128 + k];
    else if (p == 7) v = w6[n*128 + k];
    else             v = w7[n*128 + k];
    const ushort_t h = f2bf(v);
    wsWh[e] = h;
    wsWl[e] = f2bf(v - bf2f(h));
  }
  if (e < 2*NPAIR) {
    const int b  = (e >= NPAIR) ? 1 : 0;
    const int pr = e - b*NPAIR;
    const float* __restrict__ dmb = dm + b*NV*3;
    const int v0 = 2*pr, v1 = v0 + 1;
    const float x0 = dmb[v0*3+0], y0 = dmb[v0*3+1], z0 = dmb[v0*3+2];
    const float w0v = fmaf(x0,x0, fmaf(y0,y0, z0*z0));
    float x1, y1, z1, w1v;
    if (v1 < NV) {
      x1 = dmb[v1*3+0]; y1 = dmb[v1*3+1]; z1 = dmb[v1*3+2];
      w1v = fmaf(x1,x1, fmaf(y1,y1, z1*z1));
    } else { x1 = 0.f; y1 = 0.f; z1 = 0.f; w1v = 3.0e38f; }
    float* __restrict__ q = vpre + (size_t)e * 8;
    q[0] = -2.f*x0; q[1] = -2.f*x1;
    q[2] = -2.f*y0; q[3] = -2.f*y1;
    q[4] = -2.f*z0; q[5] = -2.f*z1;
    q[6] = w0v;     q[7] = w1v;
  }
}

// ---------------- Kernel 1: two-phase exact NN + features ----------------
// Block: 64 points (lane = point), 4 waves = 4 vertex quarters (wave-uniform stream).
// Phase A: packed-fp32 value-only scan of s = v^2 - 2 p.v (scalar s_load stream),
//          16 per-group (40-pair) minima in regs.
// Phase B: exact r7-verified d2 for groups with grpmin <= global_min + MARGIN, strict-<
//          ascending-index updates; 4-quarter lexicographic (d2,idx) merge.
// Exactness: |s - (d2 - p2)| <= ~1.5e-4 (both are <=5-rounding fp32 evals of v^2-2p.v,
// magnitudes <= ~128); MARGIN = 2e-3 >= 2*err, so the candidate set provably contains
// the true argmin, including clamp-tie cases; phase B replicates ref rounding exactly.
#define MARGIN 2.0e-3f

__global__ __launch_bounds__(256, 4) void k_nnfeat(
    const float* __restrict__ pts, const float* __restrict__ dm,
    const float* __restrict__ cano, const float* __restrict__ lat,
    const float* __restrict__ vpre,
    uint_t* __restrict__ feat, float* __restrict__ base3)
{
  __shared__ float sMin[256];
  __shared__ float sDr[256];
  __shared__ int   sIr[256];

  const int tid = threadIdx.x;
  const int l   = tid & 63;              // point lane
  const int wid = tid >> 6;              // vertex quarter
  const int g0  = blockIdx.x * 64;
  const int b   = blockIdx.x >> 9;       // 512 blocks per batch
  const int gpt = g0 + l;

  const float px = pts[gpt*3+0], py = pts[gpt*3+1], pz = pts[gpt*3+2];
  const float p2 = fmaf(px,px, fmaf(py,py, pz*pz));

  const int wu = __builtin_amdgcn_readfirstlane(wid);
  const float* __restrict__ vp = vpre + ((size_t)b*NPAIR + (size_t)wu*QPAIR) * 8;

  const f32x2 px2 = {px,px}, py2 = {py,py}, pz2 = {pz,pz};

  // ---- phase A: packed value-only scan, per-group minima ----
  f32x2 gm[16];
  #pragma unroll
  for (int g = 0; g < 16; ++g) {
    f32x2 m = {3.0e38f, 3.0e38f};
    const int cnt = (g == 15) ? (QPAIR - 15*40) : 40;
    const float* __restrict__ q = vp + g*40*8;
    #pragma unroll 4
    for (int t = 0; t < cnt; ++t) {
      const f32x2 vx = *(const f32x2*)(q + t*8 + 0);
      const f32x2 vy = *(const f32x2*)(q + t*8 + 2);
      const f32x2 vz = *(const f32x2*)(q + t*8 + 4);
      const f32x2 vw = *(const f32x2*)(q + t*8 + 6);
      f32x2 s = __builtin_elementwise_fma(vx, px2, vw);
      s = __builtin_elementwise_fma(vy, py2, s);
      s = __builtin_elementwise_fma(vz, pz2, s);
      m = __builtin_elementwise_min(m, s);
    }
    gm[g] = m;
  }

  f32x2 mm = gm[0];
  #pragma unroll
  for (int g = 1; g < 16; ++g) mm = __builtin_elementwise_min(mm, gm[g]);
  sMin[wid*64 + l] = fminf(mm.x, mm.y);
  __syncthreads();
  const float thr = fminf(fminf(sMin[l], sMin[64 + l]),
                          fminf(sMin[128 + l], sMin[192 + l])) + MARGIN;

  // ---- phase B: exact scan of hit groups (divergent, rare) ----
  float bs = 3.4e38f; int bi = 0;
  uint_t hm = 0;
  #pragma unroll
  for (int g = 0; g < 16; ++g)
    if (fminf(gm[g].x, gm[g].y) <= thr) hm |= (1u << g);
  const int vbase = wu * (2*QPAIR);     // first vertex index of this quarter
  while (hm != 0) {
    const int g = __ffs(hm) - 1; hm &= hm - 1;
    const int base = g*40;
    #pragma unroll 4
    for (int t = 0; t < 40; ++t) {
      const int pr = base + t;
      if (pr < QPAIR) {
        const float* q = vp + (size_t)pr*8;
        const float4 qa = *(const float4*)q;
        const float4 qb = *(const float4*)(q + 4);
        const float x0 = qa.x*-0.5f, x1 = qa.y*-0.5f;   // exact recovery of coords
        const float y0 = qa.z*-0.5f, y1 = qa.w*-0.5f;
        const float z0 = qb.x*-0.5f, z1 = qb.y*-0.5f;
        const float w0 = qb.z,       w1 = qb.w;
        const int vi0 = vbase + 2*pr;
        {
          const float dot = fmaf(px, x0, fmaf(py, y0, pz*z0));
          float d2 = fmaf(-2.f, dot, p2 + w0);          // r7-verified metric, exact
          d2 = fmaxf(d2, 0.f);
          if (d2 < bs) { bs = d2; bi = vi0; }
        }
        {
          const float dot = fmaf(px, x1, fmaf(py, y1, pz*z1));
          float d2 = fmaf(-2.f, dot, p2 + w1);
          d2 = fmaxf(d2, 0.f);
          if (d2 < bs) { bs = d2; bi = vi0 + 1; }       // pad vert: w1=3e38 -> never taken
        }
      }
    }
  }
  sDr[wid*64 + l] = bs;
  sIr[wid*64 + l] = bi;
  __syncthreads();

  // ---- features: 4 wave-uniform slices per point (verbatim r3-verified) ----
  const int p = tid & 63, slice = tid >> 6;
  const int g = g0 + p;
  float wd = sDr[p]; int wi = sIr[p];
  #pragma unroll
  for (int w_ = 1; w_ < 4; ++w_) {
    const float od = sDr[w_*64 + p]; const int oi = sIr[w_*64 + p];
    if (od < wd || (od == wd && oi < wi)) { wd = od; wi = oi; }
  }
  const float* __restrict__ dmb = dm + b * NV * 3;

  const float qx = pts[g*3+0], qy = pts[g*3+1], qz = pts[g*3+2];
  const float wgt = expf(-wd);
  const float sx = (cano[wi*3+0] - dmb[wi*3+0]) * wgt;
  const float sy = (cano[wi*3+1] - dmb[wi*3+1]) * wgt;
  const float sz = (cano[wi*3+2] - dmb[wi*3+2]) * wgt;

  uint_t* __restrict__ fr = feat + (size_t)g * FSTR;

  if (slice == 0) {
    base3[g*3+0] = qx + sx; base3[g*3+1] = qy + sy; base3[g*3+2] = qz + sz;
    fr[0] = packsplit(qx); fr[1] = packsplit(qy); fr[2] = packsplit(qz);
    #pragma unroll
    for (int f = 0; f < 3; ++f) {
      const float F = (float)(1 << f);
      float s0,c0,s1,c1,s2,c2;
      sincosf(qx*F,&s0,&c0); sincosf(qy*F,&s1,&c1); sincosf(qz*F,&s2,&c2);
      const int k = 3 + 6*f;
      fr[k+0]=packsplit(s0); fr[k+1]=packsplit(s1); fr[k+2]=packsplit(s2);
      fr[k+3]=packsplit(c0); fr[k+4]=packsplit(c1); fr[k+5]=packsplit(c2);
    }
    fr[110] = 0; fr[111] = 0;
  } else if (slice == 1) {
    #pragma unroll
    for (int f = 3; f < 7; ++f) {
      const float F = (float)(1 << f);
      float s0,c0,s1,c1,s2,c2;
      sincosf(qx*F,&s0,&c0); sincosf(qy*F,&s1,&c1); sincosf(qz*F,&s2,&c2);
      const int k = 3 + 6*f;
      fr[k+0]=packsplit(s0); fr[k+1]=packsplit(s1); fr[k+2]=packsplit(s2);
      fr[k+3]=packsplit(c0); fr[k+4]=packsplit(c1); fr[k+5]=packsplit(c2);
    }
  } else if (slice == 2) {
    #pragma unroll
    for (int f = 7; f < 10; ++f) {
      const float F = (float)(1 << f);
      float s0,c0,s1,c1,s2,c2;
      sincosf(qx*F,&s0,&c0); sincosf(qy*F,&s1,&c1); sincosf(qz*F,&s2,&c2);
      const int k = 3 + 6*f;
      fr[k+0]=packsplit(s0); fr[k+1]=packsplit(s1); fr[k+2]=packsplit(s2);
      fr[k+3]=packsplit(c0); fr[k+4]=packsplit(c1); fr[k+5]=packsplit(c2);
    }
    #pragma unroll
    for (int j = 0; j < 16; ++j) fr[78+j] = packsplit(lat[g*LATD + j]);
  } else {
    fr[63]=packsplit(sx); fr[64]=packsplit(sy); fr[65]=packsplit(sz);
    #pragma unroll
    for (int f = 0; f < 2; ++f) {
      const float F = (float)(1 << f);
      float s0,c0,s1,c1,s2,c2;
      sincosf(sx*F,&s0,&c0); sincosf(sy*F,&s1,&c1); sincosf(sz*F,&s2,&c2);
      const int k = 66 + 6*f;
      fr[k+0]=packsplit(s0); fr[k+1]=packsplit(s1); fr[k+2]=packsplit(s2);
      fr[k+3]=packsplit(c0); fr[k+4]=packsplit(c1); fr[k+5]=packsplit(c2);
    }
    #pragma unroll
    for (int j = 16; j < 32; ++j) fr[78+j] = packsplit(lat[g*LATD + j]);
  }
}

// ------------- Kernel 2: register-resident MLP (operand-swapped MFMA) — r3 verbatim -------------

union U4 { uint_t u[4]; bf16x8 v; };

__device__ __forceinline__ void zero4(f32x16 (&a)[4]) {
  #pragma unroll
  for (int i = 0; i < 4; ++i) a[i] = (f32x16)(0.f);
}

__device__ __forceinline__ void load_feat_frags(
    const uint_t* __restrict__ fr, bf16x8 (&Xh)[8], bf16x8 (&Xl)[8], int lh)
{
  #pragma unroll
  for (int ks = 0; ks < 7; ++ks) {
    const int k0 = ks*16 + lh*8;
    const uint4 ua = *(const uint4*)(fr + k0);
    const uint4 ub = *(const uint4*)(fr + k0 + 4);
    U4 H, L;
    H.u[0] = (ua.x & 0xffffu) | (ua.y << 16);
    H.u[1] = (ua.z & 0xffffu) | (ua.w << 16);
    H.u[2] = (ub.x & 0xffffu) | (ub.y << 16);
    H.u[3] = (ub.z & 0xffffu) | (ub.w << 16);
    L.u[0] = (ua.x >> 16) | (ua.y & 0xffff0000u);
    L.u[1] = (ua.z >> 16) | (ua.w & 0xffff0000u);
    L.u[2] = (ub.x >> 16) | (ub.y & 0xffff0000u);
    L.u[3] = (ub.z >> 16) | (ub.w & 0xffff0000u);
    Xh[ks] = H.v; Xl[ks] = L.v;
  }
}

__device__ __forceinline__ void load_slab(bf16x8 (&wh)[4], bf16x8 (&wl)[4],
    const ushort_t* __restrict__ Wh, const ushort_t* __restrict__ Wl,
    int ks, int l31, int lh)
{
  const int lo = l31*16 + lh*8;
  #pragma unroll
  for (int tn = 0; tn < 4; ++tn) {
    const int off = (ks*4 + tn)*512 + lo;
    wh[tn] = *(const bf16x8*)(Wh + off);
    wl[tn] = *(const bf16x8*)(Wl + off);
  }
}

__device__ __forceinline__ void mfma_slab(f32x16 (&acc)[4],
    const bf16x8 (&wh)[4], const bf16x8 (&wl)[4],
    const bf16x8& xh, const bf16x8& xl)
{
  #pragma unroll
  for (int tn = 0; tn < 4; ++tn) {
    acc[tn] = __builtin_amdgcn_mfma_f32_32x32x16_bf16(wh[tn], xh, acc[tn], 0,0,0);
    acc[tn] = __builtin_amdgcn_mfma_f32_32x32x16_bf16(wl[tn], xh, acc[tn], 0,0,0);
    acc[tn] = __builtin_amdgcn_mfma_f32_32x32x16_bf16(wh[tn], xl, acc[tn], 0,0,0);
  }
}

template<int NKS, bool TAIL>
__device__ __forceinline__ void run_panel(f32x16 (&acc)[4],
    const ushort_t* __restrict__ Wh, const ushort_t* __restrict__ Wl,
    const ushort_t* __restrict__ WhN, const ushort_t* __restrict__ WlN,
    bf16x8 (&wbh)[2][4], bf16x8 (&wbl)[2][4],
    const bf16x8 (&Xh)[8], const bf16x8 (&Xl)[8], int l31, int lh)
{
  #pragma unroll
  for (int ks = 0; ks < NKS; ++ks) {
    const int b = ks & 1;
    mfma_slab(acc, wbh[b], wbl[b], Xh[ks], Xl[ks]);
    if (ks + 2 < NKS) {
      load_slab(wbh[b], wbl[b], Wh, Wl, ks + 2, l31, lh);
    } else if (TAIL) {
      load_slab(wbh[b], wbl[b], WhN, WlN, ks & 1, l31, lh);
    }
  }
}

__device__ __forceinline__ void bias_relu(f32x16 (&acc)[4],
    const float* __restrict__ bias, int lh)
{
  #pragma unroll
  for (int tn = 0; tn < 4; ++tn)
    #pragma unroll
    for (int b = 0; b < 4; ++b) {
      const float4 b4 = *(const float4*)(bias + tn*32 + 8*b + 4*lh);
      acc[tn][4*b+0] = fmaxf(acc[tn][4*b+0] + b4.x, 0.f);
      acc[tn][4*b+1] = fmaxf(acc[tn][4*b+1] + b4.y, 0.f);
      acc[tn][4*b+2] = fmaxf(acc[tn][4*b+2] + b4.z, 0.f);
      acc[tn][4*b+3] = fmaxf(acc[tn][4*b+3] + b4.w, 0.f);
    }
}

__device__ __forceinline__ void build_frags(const f32x16 (&acc)[4],
    bf16x8 (&Xh)[8], bf16x8 (&Xl)[8], int lh)
{
  #pragma unroll
  for (int ks = 0; ks < 8; ++ks) {
    const int tn = ks >> 1;
    const int rb = 8*(ks & 1);
    const float f0 = acc[tn][rb+0], f1 = acc[tn][rb+1];
    const float f2 = acc[tn][rb+2], f3 = acc[tn][rb+3];
    const float f4 = acc[tn][rb+4], f5 = acc[tn][rb+5];
    const float f6 = acc[tn][rb+6], f7 = acc[tn][rb+7];
    const ushort_t h0=f2bf(f0), h1=f2bf(f1), h2=f2bf(f2), h3=f2bf(f3);
    const ushort_t h4=f2bf(f4), h5=f2bf(f5), h6=f2bf(f6), h7=f2bf(f7);
    const uint_t hA0 = (uint_t)h0 | ((uint_t)h1 << 16);
    const uint_t hA1 = (uint_t)h2 | ((uint_t)h3 << 16);
    const uint_t hB0 = (uint_t)h4 | ((uint_t)h5 << 16);
    const uint_t hB1 = (uint_t)h6 | ((uint_t)h7 << 16);
    const uint_t lA0 = (uint_t)f2bf(f0 - bf2f(h0)) | ((uint_t)f2bf(f1 - bf2f(h1)) << 16);
    const uint_t lA1 = (uint_t)f2bf(f2 - bf2f(h2)) | ((uint_t)f2bf(f3 - bf2f(h3)) << 16);
    const uint_t lB0 = (uint_t)f2bf(f4 - bf2f(h4)) | ((uint_t)f2bf(f5 - bf2f(h5)) << 16);
    const uint_t lB1 = (uint_t)f2bf(f6 - bf2f(h6)) | ((uint_t)f2bf(f7 - bf2f(h7)) << 16);
    const uint_t sh0 = lh ? hA0 : hB0, sh1 = lh ? hA1 : hB1;
    const uint_t sl0 = lh ? lA0 : lB0, sl1 = lh ? lA1 : lB1;
    const uint_t rh0 = __shfl_xor(sh0, 32, 64), rh1 = __shfl_xor(sh1, 32, 64);
    const uint_t rl0 = __shfl_xor(sl0, 32, 64), rl1 = __shfl_xor(sl1, 32, 64);
    U4 H, L;
    H.u[0] = lh ? rh0 : hA0;  H.u[1] = lh ? rh1 : hA1;
    H.u[2] = lh ? hB0 : rh0;  H.u[3] = lh ? hB1 : rh1;
    L.u[0] = lh ? rl0 : lA0;  L.u[1] = lh ? rl1 : lA1;
    L.u[2] = lh ? lB0 : rl0;  L.u[3] = lh ? lB1 : rl1;
    Xh[ks] = H.v; Xl[ks] = L.v;
  }
}

__global__ __launch_bounds__(256, 2) void k_mlp(
    const uint_t* __restrict__ feat, const float* __restrict__ base3,
    const ushort_t* __restrict__ wsWh, const ushort_t* __restrict__ wsWl,
    const float* __restrict__ b0, const float* __restrict__ b1,
    const float* __restrict__ b2, const float* __restrict__ b3,
    const float* __restrict__ b4, const float* __restrict__ b5,
    const float* __restrict__ b6, const float* __restrict__ b7,
    const float* __restrict__ w_out, const float* __restrict__ b_out,
    float* __restrict__ out)
{
  __shared__ __align__(16) float sF[4][32*132];   // per-wave transpose buf
  __shared__ __align__(16) float sB[8*128 + 384 + 4];

  const int tid  = threadIdx.x;
  const int lane = tid & 63, wid = tid >> 6;
  const int l31 = lane & 31, lh = lane >> 5;
  const int p0 = blockIdx.x * 128 + wid * 32;

  {
    const float* bsp[8] = {b0,b1,b2,b3,b4,b5,b6,b7};
    if (tid < 128) {
      #pragma unroll
      for (int l = 0; l < 8; ++l) sB[l*128 + tid] = bsp[l][tid];
    }
    for (int i = tid; i < 384; i += 256) sB[1024 + i] = w_out[i];
    if (tid < 3) sB[1408 + tid] = b_out[tid];
  }

  const uint_t* __restrict__ fr = feat + (size_t)(p0 + l31) * FSTR;

  bf16x8 Xh[8], Xl[8];
  bf16x8 wbh[2][4], wbl[2][4];
  f32x16 acc[4];

  load_slab(wbh[0], wbl[0], wsWh, wsWl, 0, l31, lh);
  load_slab(wbh[1], wbl[1], wsWh, wsWl, 1, l31, lh);
  load_feat_frags(fr, Xh, Xl, lh);
  __syncthreads();

  zero4(acc);
  run_panel<7,true>(acc, wsWh + 0*16384, wsWl + 0*16384,
                         wsWh + 1*16384, wsWl + 1*16384, wbh, wbl, Xh, Xl, l31, lh);
  bias_relu(acc, sB + 0*128, lh);
  build_frags(acc, Xh, Xl, lh);

  zero4(acc);
  run_panel<8,true>(acc, wsWh + 1*16384, wsWl + 1*16384,
                         wsWh + 2*16384, wsWl + 2*16384, wbh, wbl, Xh, Xl, l31, lh);
  bias_relu(acc, sB + 1*128, lh);
  build_frags(acc, Xh, Xl, lh);

  zero4(acc);
  run_panel<8,true>(acc, wsWh + 2*16384, wsWl + 2*16384,
                         wsWh + 3*16384, wsWl + 3*16384, wbh, wbl, Xh, Xl, l31, lh);
  bias_relu(acc, sB + 2*128, lh);
  build_frags(acc, Xh, Xl, lh);

  zero4(acc);
  run_panel<8,true>(acc, wsWh + 3*16384, wsWl + 3*16384,
                         wsWh + 5*16384, wsWl + 5*16384, wbh, wbl, Xh, Xl, l31, lh);
  bias_relu(acc, sB + 3*128, lh);
  build_frags(acc, Xh, Xl, lh);

  zero4(acc);
  run_panel<8,true>(acc, wsWh + 5*16384, wsWl + 5*16384,
                         wsWh + 4*16384, wsWl + 4*16384, wbh, wbl, Xh, Xl, l31, lh);
  load_feat_frags(fr, Xh, Xl, lh);
  run_panel<7,true>(acc, wsWh + 4*16384, wsWl + 4*16384,
                         wsWh + 6*16384, wsWl + 6*16384, wbh, wbl, Xh, Xl, l31, lh);
  bias_relu(acc, sB + 4*128, lh);
  build_frags(acc, Xh, Xl, lh);

  zero4(acc);
  run_panel<8,true>(acc, wsWh + 6*16384, wsWl + 6*16384,
                         wsWh + 7*16384, wsWl + 7*16384, wbh, wbl, Xh, Xl, l31, lh);
  bias_relu(acc, sB + 5*128, lh);
  build_frags(acc, Xh, Xl, lh);

  zero4(acc);
  run_panel<8,true>(acc, wsWh + 7*16384, wsWl + 7*16384,
                         wsWh + 8*16384, wsWl + 8*16384, wbh, wbl, Xh, Xl, l31, lh);
  bias_relu(acc, sB + 6*128, lh);
  build_frags(acc, Xh, Xl, lh);

  zero4(acc);
  run_panel<8,false>(acc, wsWh + 8*16384, wsWl + 8*16384,
                          (const ushort_t*)0, (const ushort_t*)0, wbh, wbl, Xh, Xl, l31, lh);

  float* __restrict__ sFw = &sF[wid][0];
  #pragma unroll
  for (int tn = 0; tn < 4; ++tn)
    #pragma unroll
    for (int b = 0; b < 4; ++b) {
      const int n0 = tn*32 + 8*b + 4*lh;
      const float4 bv = *(const float4*)(sB + 7*128 + n0);
      const float v0 = acc[tn][4*b+0] + bv.x;
      const float v1 = acc[tn][4*b+1] + bv.y;
      const float v2 = acc[tn][4*b+2] + bv.z;
      const float v3 = acc[tn][4*b+3] + bv.w;
      *(float4*)(sFw + l31*132 + n0) = make_float4(v0, v1, v2, v3);
      acc[tn][4*b+0] = fmaxf(v0, 0.f);
      acc[tn][4*b+1] = fmaxf(v1, 0.f);
      acc[tn][4*b+2] = fmaxf(v2, 0.f);
      acc[tn][4*b+3] = fmaxf(v3, 0.f);
    }

  asm volatile("s_waitcnt lgkmcnt(0)" ::: "memory");
  __builtin_amdgcn_sched_barrier(0);

  float* __restrict__ out1 = out + (size_t)NPTS * 3;
  #pragma unroll
  for (int i = 0; i < 16; ++i) {
    const int idx = i*64 + lane;
    const int p = idx >> 5, q = idx & 31;
    const float4 v = *(const float4*)(sFw + p*132 + q*4);
    *(float4*)(out1 + (size_t)(p0 + p)*128 + q*4) = v;
  }

  float dotc[3];
  #pragma unroll
  for (int c = 0; c < 3; ++c) {
    float a = 0.f;
    #pragma unroll
    for (int tn = 0; tn < 4; ++tn)
      #pragma unroll
      for (int b = 0; b < 4; ++b) {
        const int n0 = tn*32 + 8*b + 4*lh;
        const float4 w4 = *(const float4*)(sB + 1024 + c*128 + n0);
        a = fmaf(acc[tn][4*b+0], w4.x, a);
        a = fmaf(acc[tn][4*b+1], w4.y, a);
        a = fmaf(acc[tn][4*b+2], w4.z, a);
        a = fmaf(acc[tn][4*b+3], w4.w, a);
      }
    a += __shfl_xor(a, 32, 64);
    dotc[c] = a;
  }
  if (lh == 0) {
    const int g = p0 + l31;
    #pragma unroll
    for (int c = 0; c < 3; ++c)
      out[g*3 + c] = base3[g*3 + c] + dotc[c] + sB[1408 + c];
  }
}

extern "C" void kernel_launch(void* const* d_in, const int* in_sizes, int n_in,
                              void* d_out, int out_size, void* d_ws, size_t ws_size,
                              hipStream_t stream)
{
  const float* pts  = (const float*)d_in[0];
  const float* dm   = (const float*)d_in[1];
  const float* cano = (const float*)d_in[2];
  const float* lat  = (const float*)d_in[3];
  const float* w[8]; const float* b[8];
  for (int i = 0; i < 8; ++i) {
    w[i] = (const float*)d_in[4 + 2*i];
    b[i] = (const float*)d_in[5 + 2*i];
  }
  const float* w_out = (const float*)d_in[20];
  const float* b_out = (const float*)d_in[21];
  float* out = (float*)d_out;

  // ws: feat [NPTS][112] uint (29.36MB) | base3 (786KB) | wsWh (288KB) | wsWl (288KB)
  //     | vpre 2*2512*8 floats (161KB)
  uint_t*   feat  = (uint_t*)d_ws;
  float*    base3 = (float*)((char*)d_ws + (size_t)NPTS*FSTR*4);
  ushort_t* wsWh  = (ushort_t*)((char*)base3 + (size_t)NPTS*3*4);
  ushort_t* wsWl  = wsWh + 147456;
  float*    vpre  = (float*)(wsWl + 147456);

  k_prep<<<576, 256, 0, stream>>>(dm,
      w[0],w[1],w[2],w[3],w[4],w[5],w[6],w[7], wsWh, wsWl, vpre);
  k_nnfeat<<<1024, 256, 0, stream>>>(pts, dm, cano, lat, vpre, feat, base3);
  k_mlp<<<NPTS/128, 256, 0, stream>>>(feat, base3, wsWh, wsWl,
      b[0],b[1],b[2],b[3],b[4],b[5],b[6],b[7], w_out, b_out, out);
}